// Round 1
// baseline (2519.899 us; speedup 1.0000x reference)
//
#include <hip/hip_runtime.h>
#include <math.h>

#define BATCH 64
#define TT 24
#define HW 65536
#define PIX 50
#define NROWS 3200   // BATCH*PIX
#define NN 24
#define GAMMA_F 0.001f
#define INVG 1000.0f
#define BIGF 100000000.0f

// ---------------- Kernel 1: per-batch top-50 of static_ch ----------------
// Reproduces lax.top_k ordering: descending value, ties -> lower index first.
// Iterative: select max key strictly less than previously-selected key.
__global__ void topk_kernel(const float* __restrict__ mask, int* __restrict__ topk) {
    int b = blockIdx.x;
    const float* m = mask + (size_t)b * HW;
    __shared__ float sv[256];
    __shared__ int   si[256];
    int tid = threadIdx.x;
    float pv = INFINITY; int pi = -1;   // previous selected key (none yet)
    for (int k = 0; k < PIX; ++k) {
        float bv = -INFINITY; int bi = HW;
        for (int i = tid; i < HW; i += 256) {
            float v = m[i];
            // key(v,i) strictly less than key(pv,pi) under (value desc, idx asc)
            bool ok = (v < pv) || (v == pv && i > pi);
            if (ok && (v > bv || (v == bv && i < bi))) { bv = v; bi = i; }
        }
        sv[tid] = bv; si[tid] = bi;
        __syncthreads();
        for (int off = 128; off > 0; off >>= 1) {
            if (tid < off) {
                float ov = sv[tid + off]; int oi = si[tid + off];
                if (ov > sv[tid] || (ov == sv[tid] && oi < si[tid])) {
                    sv[tid] = ov; si[tid] = oi;
                }
            }
            __syncthreads();
        }
        pv = sv[0]; pi = si[0];
        if (tid == 0) topk[b * PIX + k] = pi;
        __syncthreads();   // protect sv/si before next iteration's writes
    }
}

// ---------------- Kernel 2: soft-DTW forward + analytic backward ----------------
// One wave (64 lanes) per row n of the scrambled (3200, 24) sequences.
// 4 waves per block. Anti-diagonal wavefront; R and E live in LDS.
__global__ __launch_bounds__(256) void dtw_kernel(
        const float* __restrict__ pred, const float* __restrict__ truth,
        const int* __restrict__ topk,
        float* __restrict__ shape_part, float* __restrict__ temp_part) {
    __shared__ float Rm[4][26][27];
    __shared__ float Em[4][26][27];
    __shared__ float tv[4][NN];
    __shared__ float pvv[4][NN];

    int tid  = threadIdx.x;
    int w    = tid >> 6;
    int lane = tid & 63;
    int n    = blockIdx.x * 4 + w;
    float (*R)[27] = Rm[w];
    float (*E)[27] = Em[w];

    // ---- gather the 24 (true, pred) values for this row (scrambled reshape) ----
    if (lane < NN) {
        int f  = n * NN + lane;          // flat index over (b, t, p) row-major
        int b  = f / (TT * PIX);         // /1200
        int r  = f - b * (TT * PIX);
        int t  = r / PIX;
        int p  = r - t * PIX;
        int hw = topk[b * PIX + p];
        size_t base = (size_t)(b * TT + t) * HW + (size_t)hw;
        tv[w][lane]  = truth[base];
        pvv[w][lane] = pred[base];
    }

    // ---- init R boundaries and zero E ----
    if (lane < 26) {
        R[0][lane]  = (lane == 0) ? 0.0f : BIGF;   // top boundary
        R[lane][0]  = (lane == 0) ? 0.0f : BIGF;   // left boundary
        R[lane][25] = -INFINITY;                   // backward pad col
        R[25][lane] = -INFINITY;                   // backward pad row
    }
    for (int idx = lane; idx < 26 * 27; idx += 64) ((float*)E)[idx] = 0.0f;
    __syncthreads();

    // ---- forward: R[i][j] = D[i][j] + softmin_gamma(diag, up, left) ----
    for (int s = 2; s <= 2 * NN; ++s) {
        if (lane < NN) {
            int j = lane + 1;
            int i = s - j;
            if (i >= 1 && i <= NN) {
                float diag = R[i - 1][j - 1];
                float up   = R[i - 1][j];
                float left = R[i][j - 1];
                float mn = fminf(diag, fminf(up, left));
                float z = __expf((mn - diag) * INVG)
                        + __expf((mn - up)   * INVG)
                        + __expf((mn - left) * INVG);
                float d = tv[w][i - 1] - pvv[w][j - 1];
                R[i][j] = d * d + mn - GAMMA_F * __logf(z);
            }
        }
        __syncthreads();
    }

    if (lane == 0) {
        R[25][25] = R[NN][NN];
        E[25][25] = 1.0f;
    }
    __syncthreads();

    // ---- backward: E[i][j] = a*E[i+1][j] + b*E[i][j+1] + c*E[i+1][j+1] ----
    for (int s = 2 * NN; s >= 2; --s) {
        if (lane < NN) {
            int j = lane + 1;
            int i = s - j;
            if (i >= 1 && i <= NN) {
                float rij = R[i][j];
                float da = 0.0f, db = 0.0f, dc = 0.0f;
                if (i + 1 <= NN) { float d = tv[w][i] - pvv[w][j - 1]; da = d * d; }
                if (j + 1 <= NN) { float d = tv[w][i - 1] - pvv[w][j]; db = d * d; }
                if (i + 1 <= NN && j + 1 <= NN) { float d = tv[w][i] - pvv[w][j]; dc = d * d; }
                float a = __expf((R[i + 1][j]     - rij - da) * INVG);
                float bb = __expf((R[i][j + 1]    - rij - db) * INVG);
                float c = __expf((R[i + 1][j + 1] - rij - dc) * INVG);
                E[i][j] = a * E[i + 1][j] + bb * E[i][j + 1] + c * E[i + 1][j + 1];
            }
        }
        __syncthreads();
    }

    // ---- per-row reductions ----
    float colE = 0.0f;
    if (lane < NN) {
        int j = lane + 1;
        for (int i = 1; i <= NN; ++i) {
            float dd = (float)(i - j);
            colE += E[i][j] * dd * dd;
        }
        E[0][lane] = colE;   // row 0 of E is unused; reuse for reduction
    }
    __syncthreads();
    if (lane == 0) {
        float ts = 0.0f;
        for (int j = 0; j < NN; ++j) ts += E[0][j];
        temp_part[n]  = ts;
        shape_part[n] = R[NN][NN];
    }
}

// ---------------- Kernel 3: deterministic final reduction ----------------
__global__ void finalize_kernel(const float* __restrict__ shape_part,
                                const float* __restrict__ temp_part,
                                float* __restrict__ out) {
    __shared__ double sd[256];
    __shared__ double td[256];
    int tid = threadIdx.x;
    double s = 0.0, t = 0.0;
    for (int i = tid; i < NROWS; i += 256) {
        s += (double)shape_part[i];
        t += (double)temp_part[i];
    }
    sd[tid] = s; td[tid] = t;
    __syncthreads();
    for (int off = 128; off > 0; off >>= 1) {
        if (tid < off) { sd[tid] += sd[tid + off]; td[tid] += td[tid + off]; }
        __syncthreads();
    }
    if (tid == 0) {
        double loss_shape    = sd[0] / (double)NROWS;
        double loss_temporal = td[0] / ((double)NROWS * (double)(NN * NN));
        out[0] = (float)(0.1 * loss_shape + 0.9 * loss_temporal);
    }
}

extern "C" void kernel_launch(void* const* d_in, const int* in_sizes, int n_in,
                              void* d_out, int out_size, void* d_ws, size_t ws_size,
                              hipStream_t stream) {
    const float* pred  = (const float*)d_in[0];
    const float* truth = (const float*)d_in[1];
    const float* mask  = (const float*)d_in[2];

    int*   topk       = (int*)d_ws;                                   // 64*50 ints
    float* shape_part = (float*)((char*)d_ws + BATCH * PIX * sizeof(int));
    float* temp_part  = shape_part + NROWS;                           // total ~38.4 KB

    topk_kernel<<<BATCH, 256, 0, stream>>>(mask, topk);
    dtw_kernel<<<NROWS / 4, 256, 0, stream>>>(pred, truth, topk, shape_part, temp_part);
    finalize_kernel<<<1, 256, 0, stream>>>(shape_part, temp_part, (float*)d_out);
}

// Round 2
// 96.808 us; speedup vs baseline: 26.0299x; 26.0299x over previous
//
#include <hip/hip_runtime.h>
#include <math.h>

#define BATCH 64
#define TT 24
#define HW 65536
#define PIX 50
#define NROWS 3200   // BATCH*PIX
#define NN 24
#define GAMMA_F 0.001f
#define INVG 1000.0f
#define BIGF 100000000.0f
#define CAP 512

__device__ __forceinline__ unsigned ordered_key(float f) {
    unsigned u = __float_as_uint(f);
    return (u & 0x80000000u) ? ~u : (u | 0x80000000u);
}

// ---------------- Kernel 1: per-batch top-50 via 2-level radix select ----
// Exact lax.top_k semantics: value descending, ties -> lower index first.
__global__ __launch_bounds__(1024) void topk_kernel(const float* __restrict__ mask,
                                                    int* __restrict__ topk) {
    int b = blockIdx.x;
    const float* m = mask + (size_t)b * HW;
    __shared__ unsigned hist[4096];
    __shared__ unsigned sufA[1024];
    __shared__ unsigned sufB[1024];
    __shared__ unsigned s_bin, s_above;
    __shared__ unsigned ncand;
    __shared__ unsigned candKey[CAP];
    __shared__ unsigned candIdx[CAP];

    int tid = threadIdx.x;
    if (tid == 0) ncand = 0;

    unsigned prefHi = 0, maskHi = 0;   // accumulated key prefix / mask
    unsigned Kwant = PIX;

    for (int pass = 0; pass < 2; ++pass) {
        int sh = (pass == 0) ? 20 : 8;

        for (int i = tid; i < 4096; i += 1024) hist[i] = 0;
        __syncthreads();
        for (int i = tid; i < HW; i += 1024) {
            unsigned key = ordered_key(m[i]);
            if ((key & maskHi) == prefHi)
                atomicAdd(&hist[(key >> sh) & 0xFFFu], 1u);
        }
        __syncthreads();

        // per-thread partial over 4 bins, then Hillis-Steele suffix scan
        unsigned p = hist[4 * tid] + hist[4 * tid + 1] + hist[4 * tid + 2] + hist[4 * tid + 3];
        sufA[tid] = p;
        __syncthreads();
        unsigned* src = sufA;
        unsigned* dst = sufB;
        for (int off = 1; off < 1024; off <<= 1) {
            unsigned v = src[tid] + ((tid + off < 1024) ? src[tid + off] : 0u);
            dst[tid] = v;
            __syncthreads();
            unsigned* tmp = src; src = dst; dst = tmp;
        }
        // src[t] = suffix sum of partials from t. Find crossing bin:
        // B = max{bin : S(bin) >= Kwant}, where S(bin) = count of keys in bins >= bin.
        {
            unsigned Sprev = (tid < 1023) ? src[tid + 1] : 0u;  // S(4t+4)
            for (int bsub = 3; bsub >= 0; --bsub) {
                int bin = 4 * tid + bsub;
                unsigned S = Sprev + hist[bin];
                if (S >= Kwant && Sprev < Kwant) { s_bin = (unsigned)bin; s_above = Sprev; }
                Sprev = S;
            }
        }
        __syncthreads();
        Kwant  -= s_above;                 // still needed from within selected bin
        prefHi |= s_bin << sh;
        maskHi |= 0xFFFu << sh;
        __syncthreads();
    }

    // collect candidates: key >= prefHi ((B1<<20)|(B2<<8)); count in [PIX, PIX+~subbin)
    for (int i = tid; i < HW; i += 1024) {
        unsigned key = ordered_key(m[i]);
        if (key >= prefHi) {
            unsigned pos = atomicAdd(&ncand, 1u);
            if (pos < CAP) { candKey[pos] = key; candIdx[pos] = (unsigned)i; }
        }
    }
    __syncthreads();

    int nc = (int)min(ncand, (unsigned)CAP);
    if (tid < nc) {
        // composite: value desc, then index asc (unique -> exact ranks)
        unsigned long long me =
            ((unsigned long long)candKey[tid] << 32) | (unsigned long long)(~candIdx[tid]);
        int rank = 0;
        for (int j = 0; j < nc; ++j) {
            unsigned long long o =
                ((unsigned long long)candKey[j] << 32) | (unsigned long long)(~candIdx[j]);
            rank += (o > me);
        }
        if (rank < PIX) topk[b * PIX + rank] = (int)candIdx[tid];
    }
}

// ---------------- Kernel 2: soft-DTW forward + analytic backward ----------------
// One wave (64 lanes) per row n of the scrambled (3200, 24) sequences.
// 4 waves per block. Anti-diagonal wavefront; R and E live in LDS.
__global__ __launch_bounds__(256) void dtw_kernel(
        const float* __restrict__ pred, const float* __restrict__ truth,
        const int* __restrict__ topk,
        float* __restrict__ shape_part, float* __restrict__ temp_part) {
    __shared__ float Rm[4][26][27];
    __shared__ float Em[4][26][27];
    __shared__ float tv[4][NN];
    __shared__ float pvv[4][NN];

    int tid  = threadIdx.x;
    int w    = tid >> 6;
    int lane = tid & 63;
    int n    = blockIdx.x * 4 + w;
    float (*R)[27] = Rm[w];
    float (*E)[27] = Em[w];

    // ---- gather the 24 (true, pred) values for this row (scrambled reshape) ----
    if (lane < NN) {
        int f  = n * NN + lane;          // flat index over (b, t, p) row-major
        int b  = f / (TT * PIX);         // /1200
        int r  = f - b * (TT * PIX);
        int t  = r / PIX;
        int p  = r - t * PIX;
        int hw = topk[b * PIX + p];
        size_t base = (size_t)(b * TT + t) * HW + (size_t)hw;
        tv[w][lane]  = truth[base];
        pvv[w][lane] = pred[base];
    }

    // ---- init R boundaries and zero E ----
    if (lane < 26) {
        R[0][lane]  = (lane == 0) ? 0.0f : BIGF;   // top boundary
        R[lane][0]  = (lane == 0) ? 0.0f : BIGF;   // left boundary
        R[lane][25] = -INFINITY;                   // backward pad col
        R[25][lane] = -INFINITY;                   // backward pad row
    }
    for (int idx = lane; idx < 26 * 27; idx += 64) ((float*)E)[idx] = 0.0f;
    __syncthreads();

    // ---- forward: R[i][j] = D[i][j] + softmin_gamma(diag, up, left) ----
    for (int s = 2; s <= 2 * NN; ++s) {
        if (lane < NN) {
            int j = lane + 1;
            int i = s - j;
            if (i >= 1 && i <= NN) {
                float diag = R[i - 1][j - 1];
                float up   = R[i - 1][j];
                float left = R[i][j - 1];
                float mn = fminf(diag, fminf(up, left));
                float z = __expf((mn - diag) * INVG)
                        + __expf((mn - up)   * INVG)
                        + __expf((mn - left) * INVG);
                float d = tv[w][i - 1] - pvv[w][j - 1];
                R[i][j] = d * d + mn - GAMMA_F * __logf(z);
            }
        }
        __syncthreads();
    }

    if (lane == 0) {
        R[25][25] = R[NN][NN];
        E[25][25] = 1.0f;
    }
    __syncthreads();

    // ---- backward: E[i][j] = a*E[i+1][j] + b*E[i][j+1] + c*E[i+1][j+1] ----
    for (int s = 2 * NN; s >= 2; --s) {
        if (lane < NN) {
            int j = lane + 1;
            int i = s - j;
            if (i >= 1 && i <= NN) {
                float rij = R[i][j];
                float da = 0.0f, db = 0.0f, dc = 0.0f;
                if (i + 1 <= NN) { float d = tv[w][i] - pvv[w][j - 1]; da = d * d; }
                if (j + 1 <= NN) { float d = tv[w][i - 1] - pvv[w][j]; db = d * d; }
                if (i + 1 <= NN && j + 1 <= NN) { float d = tv[w][i] - pvv[w][j]; dc = d * d; }
                float a  = __expf((R[i + 1][j]     - rij - da) * INVG);
                float bb = __expf((R[i][j + 1]     - rij - db) * INVG);
                float c  = __expf((R[i + 1][j + 1] - rij - dc) * INVG);
                E[i][j] = a * E[i + 1][j] + bb * E[i][j + 1] + c * E[i + 1][j + 1];
            }
        }
        __syncthreads();
    }

    // ---- per-row reductions ----
    float colE = 0.0f;
    if (lane < NN) {
        int j = lane + 1;
        for (int i = 1; i <= NN; ++i) {
            float dd = (float)(i - j);
            colE += E[i][j] * dd * dd;
        }
        E[0][lane] = colE;   // row 0 of E is unused; reuse for reduction
    }
    __syncthreads();
    if (lane == 0) {
        float ts = 0.0f;
        for (int j = 0; j < NN; ++j) ts += E[0][j];
        temp_part[n]  = ts;
        shape_part[n] = R[NN][NN];
    }
}

// ---------------- Kernel 3: deterministic final reduction ----------------
__global__ void finalize_kernel(const float* __restrict__ shape_part,
                                const float* __restrict__ temp_part,
                                float* __restrict__ out) {
    __shared__ double sd[256];
    __shared__ double td[256];
    int tid = threadIdx.x;
    double s = 0.0, t = 0.0;
    for (int i = tid; i < NROWS; i += 256) {
        s += (double)shape_part[i];
        t += (double)temp_part[i];
    }
    sd[tid] = s; td[tid] = t;
    __syncthreads();
    for (int off = 128; off > 0; off >>= 1) {
        if (tid < off) { sd[tid] += sd[tid + off]; td[tid] += td[tid + off]; }
        __syncthreads();
    }
    if (tid == 0) {
        double loss_shape    = sd[0] / (double)NROWS;
        double loss_temporal = td[0] / ((double)NROWS * (double)(NN * NN));
        out[0] = (float)(0.1 * loss_shape + 0.9 * loss_temporal);
    }
}

extern "C" void kernel_launch(void* const* d_in, const int* in_sizes, int n_in,
                              void* d_out, int out_size, void* d_ws, size_t ws_size,
                              hipStream_t stream) {
    const float* pred  = (const float*)d_in[0];
    const float* truth = (const float*)d_in[1];
    const float* mask  = (const float*)d_in[2];

    int*   topk       = (int*)d_ws;                                   // 64*50 ints
    float* shape_part = (float*)((char*)d_ws + BATCH * PIX * sizeof(int));
    float* temp_part  = shape_part + NROWS;                           // total ~38.4 KB

    topk_kernel<<<BATCH, 1024, 0, stream>>>(mask, topk);
    dtw_kernel<<<NROWS / 4, 256, 0, stream>>>(pred, truth, topk, shape_part, temp_part);
    finalize_kernel<<<1, 256, 0, stream>>>(shape_part, temp_part, (float*)d_out);
}

// Round 3
// 86.921 us; speedup vs baseline: 28.9907x; 1.1137x over previous
//
#include <hip/hip_runtime.h>
#include <math.h>

#define BATCH 64
#define TT 24
#define HW 65536
#define PIX 50
#define NROWS 3200   // BATCH*PIX
#define NN 24
#define GAMMA_F 0.001f
#define INVG 1000.0f
#define BIGF 100000000.0f
#define CAP 2048
#define NBIN 32768   // bins over ordered-key bits [31:17]

__device__ __forceinline__ unsigned ordered_key(float f) {
    unsigned u = __float_as_uint(f);
    return (u & 0x80000000u) ? ~u : (u | 0x80000000u);
}

// ---------------- Kernel 1: per-batch top-50 via 1-level radix + rank ----
// Exact lax.top_k semantics: value descending, ties -> lower index first.
// One 1024-thread block per batch. 152 KB LDS (gfx950 allows up to 160 KB/WG).
__global__ __launch_bounds__(1024) void topk_kernel(const float* __restrict__ mask,
                                                    int* __restrict__ topk) {
    int b = blockIdx.x;
    const float4* m4 = (const float4*)(mask + (size_t)b * HW);
    __shared__ unsigned hist[NBIN];      // 128 KB
    __shared__ unsigned sufA[1024];
    __shared__ unsigned sufB[1024];
    __shared__ unsigned s_bin;
    __shared__ unsigned ncand;
    __shared__ unsigned candKey[CAP];
    __shared__ unsigned candIdx[CAP];

    int tid = threadIdx.x;
    if (tid == 0) ncand = 0;
    // zero hist, conflict-free (consecutive lanes -> consecutive banks)
    for (int k = 0; k < NBIN / 1024; ++k) hist[tid + 1024 * k] = 0;
    __syncthreads();

    // ---- single histogram pass (vectorized float4 reads) ----
    for (int c = tid; c < HW / 4; c += 1024) {
        float4 v = m4[c];
        atomicAdd(&hist[ordered_key(v.x) >> 17], 1u);
        atomicAdd(&hist[ordered_key(v.y) >> 17], 1u);
        atomicAdd(&hist[ordered_key(v.z) >> 17], 1u);
        atomicAdd(&hist[ordered_key(v.w) >> 17], 1u);
    }
    __syncthreads();

    // ---- per-thread partial over 32 consecutive bins (rotated to dodge banks) ----
    int base = tid * 32;
    int rot  = tid & 31;
    unsigned p = 0;
    for (int k = 0; k < 32; ++k) p += hist[base + ((k + rot) & 31)];
    sufA[tid] = p;
    __syncthreads();

    // ---- Hillis-Steele suffix scan of 1024 partials ----
    unsigned* src = sufA;
    unsigned* dst = sufB;
    for (int off = 1; off < 1024; off <<= 1) {
        unsigned v = src[tid] + ((tid + off < 1024) ? src[tid + off] : 0u);
        dst[tid] = v;
        __syncthreads();
        unsigned* tmp = src; src = dst; dst = tmp;
    }

    // ---- find crossing bin: max bin with S(bin) >= PIX ----
    {
        unsigned Sprev = (tid < 1023) ? src[tid + 1] : 0u;   // S(32t+32)
        for (int bsub = 31; bsub >= 0; --bsub) {
            unsigned S = Sprev + hist[base + bsub];
            if (S >= PIX && Sprev < PIX) s_bin = (unsigned)(base + bsub);
            Sprev = S;
        }
    }
    __syncthreads();
    unsigned thresh = s_bin << 17;

    // ---- collect candidates (L2-resident second scan) ----
    for (int c = tid; c < HW / 4; c += 1024) {
        float4 v = m4[c];
        float vv[4] = {v.x, v.y, v.z, v.w};
        for (int e = 0; e < 4; ++e) {
            unsigned key = ordered_key(vv[e]);
            if (key >= thresh) {
                unsigned pos = atomicAdd(&ncand, 1u);
                if (pos < CAP) { candKey[pos] = key; candIdx[pos] = (unsigned)(4 * c + e); }
            }
        }
    }
    __syncthreads();

    // ---- exact ranking among candidates: value desc, index asc ----
    int nc = (int)min(ncand, (unsigned)CAP);
    if (tid < nc) {
        unsigned long long me =
            ((unsigned long long)candKey[tid] << 32) | (unsigned long long)(~candIdx[tid]);
        int rank = 0;
        for (int j = 0; j < nc; ++j) {
            unsigned long long o =
                ((unsigned long long)candKey[j] << 32) | (unsigned long long)(~candIdx[j]);
            rank += (o > me);
        }
        if (rank < PIX) topk[b * PIX + rank] = (int)candIdx[tid];
    }
}

// ---------------- Kernel 2: soft-DTW forward + analytic backward ----------------
// ONE wave per block (single-wave barriers are ~free); one row n per block.
__global__ __launch_bounds__(64) void dtw_kernel(
        const float* __restrict__ pred, const float* __restrict__ truth,
        const int* __restrict__ topk,
        float* __restrict__ shape_part, float* __restrict__ temp_part) {
    __shared__ float R[26][27];
    __shared__ float E[26][27];
    __shared__ float tv[NN];
    __shared__ float pvv[NN];

    int lane = threadIdx.x;
    int n    = blockIdx.x;

    // ---- gather the 24 (true, pred) values for this row (scrambled reshape) ----
    if (lane < NN) {
        int f  = n * NN + lane;          // flat index over (b, t, p) row-major
        int b  = f / (TT * PIX);         // /1200
        int r  = f - b * (TT * PIX);
        int t  = r / PIX;
        int pp = r - t * PIX;
        int hw = topk[b * PIX + pp];
        size_t bidx = (size_t)(b * TT + t) * HW + (size_t)hw;
        tv[lane]  = truth[bidx];
        pvv[lane] = pred[bidx];
    }

    // ---- init R boundaries and zero E ----
    if (lane < 26) {
        R[0][lane]  = (lane == 0) ? 0.0f : BIGF;   // top boundary
        R[lane][0]  = (lane == 0) ? 0.0f : BIGF;   // left boundary
        R[lane][25] = -INFINITY;                   // backward pad col
        R[25][lane] = -INFINITY;                   // backward pad row
    }
    for (int idx = lane; idx < 26 * 27; idx += 64) ((float*)E)[idx] = 0.0f;
    __syncthreads();

    // ---- forward: R[i][j] = D[i][j] + softmin_gamma(diag, up, left) ----
    for (int s = 2; s <= 2 * NN; ++s) {
        if (lane < NN) {
            int j = lane + 1;
            int i = s - j;
            if (i >= 1 && i <= NN) {
                float diag = R[i - 1][j - 1];
                float up   = R[i - 1][j];
                float left = R[i][j - 1];
                float mn = fminf(diag, fminf(up, left));
                float z = __expf((mn - diag) * INVG)
                        + __expf((mn - up)   * INVG)
                        + __expf((mn - left) * INVG);
                float d = tv[i - 1] - pvv[j - 1];
                R[i][j] = d * d + mn - GAMMA_F * __logf(z);
            }
        }
        __syncthreads();
    }

    if (lane == 0) {
        R[25][25] = R[NN][NN];
        E[25][25] = 1.0f;
    }
    __syncthreads();

    // ---- backward: E[i][j] = a*E[i+1][j] + b*E[i][j+1] + c*E[i+1][j+1] ----
    for (int s = 2 * NN; s >= 2; --s) {
        if (lane < NN) {
            int j = lane + 1;
            int i = s - j;
            if (i >= 1 && i <= NN) {
                float rij = R[i][j];
                float da = 0.0f, db = 0.0f, dc = 0.0f;
                if (i + 1 <= NN) { float d = tv[i] - pvv[j - 1]; da = d * d; }
                if (j + 1 <= NN) { float d = tv[i - 1] - pvv[j]; db = d * d; }
                if (i + 1 <= NN && j + 1 <= NN) { float d = tv[i] - pvv[j]; dc = d * d; }
                float a  = __expf((R[i + 1][j]     - rij - da) * INVG);
                float bb = __expf((R[i][j + 1]     - rij - db) * INVG);
                float c  = __expf((R[i + 1][j + 1] - rij - dc) * INVG);
                E[i][j] = a * E[i + 1][j] + bb * E[i][j + 1] + c * E[i + 1][j + 1];
            }
        }
        __syncthreads();
    }

    // ---- per-row reductions ----
    if (lane < NN) {
        int j = lane + 1;
        float colE = 0.0f;
        for (int i = 1; i <= NN; ++i) {
            float dd = (float)(i - j);
            colE += E[i][j] * dd * dd;
        }
        E[0][lane] = colE;   // row 0 of E is unused; reuse for reduction
    }
    __syncthreads();
    if (lane == 0) {
        float ts = 0.0f;
        for (int j = 0; j < NN; ++j) ts += E[0][j];
        temp_part[n]  = ts;
        shape_part[n] = R[NN][NN];
    }
}

// ---------------- Kernel 3: deterministic final reduction ----------------
__global__ void finalize_kernel(const float* __restrict__ shape_part,
                                const float* __restrict__ temp_part,
                                float* __restrict__ out) {
    __shared__ double sd[256];
    __shared__ double td[256];
    int tid = threadIdx.x;
    double s = 0.0, t = 0.0;
    for (int i = tid; i < NROWS; i += 256) {
        s += (double)shape_part[i];
        t += (double)temp_part[i];
    }
    sd[tid] = s; td[tid] = t;
    __syncthreads();
    for (int off = 128; off > 0; off >>= 1) {
        if (tid < off) { sd[tid] += sd[tid + off]; td[tid] += td[tid + off]; }
        __syncthreads();
    }
    if (tid == 0) {
        double loss_shape    = sd[0] / (double)NROWS;
        double loss_temporal = td[0] / ((double)NROWS * (double)(NN * NN));
        out[0] = (float)(0.1 * loss_shape + 0.9 * loss_temporal);
    }
}

extern "C" void kernel_launch(void* const* d_in, const int* in_sizes, int n_in,
                              void* d_out, int out_size, void* d_ws, size_t ws_size,
                              hipStream_t stream) {
    const float* pred  = (const float*)d_in[0];
    const float* truth = (const float*)d_in[1];
    const float* mask  = (const float*)d_in[2];

    int*   topk       = (int*)d_ws;                                   // 64*50 ints
    float* shape_part = (float*)((char*)d_ws + BATCH * PIX * sizeof(int));
    float* temp_part  = shape_part + NROWS;                           // total ~38.4 KB

    topk_kernel<<<BATCH, 1024, 0, stream>>>(mask, topk);
    dtw_kernel<<<NROWS, 64, 0, stream>>>(pred, truth, topk, shape_part, temp_part);
    finalize_kernel<<<1, 256, 0, stream>>>(shape_part, temp_part, (float*)d_out);
}